// Round 7
// baseline (680.642 us; speedup 1.0000x reference)
//
#include <hip/hip_runtime.h>

#define N_USERS 100000
#define N_ITEMS 50000
#define N_NODES 150000
#define EMBED   64
#define NNZV    4000000
#define BATCH   4096
// bucket = row >> 9 : 512 rows per bucket, ceil(150000/512) = 293 buckets
#define NBKT    293
// fixed staging capacity per bucket: mean 13,653 + ~21 sigma
#define CAP     16128
// scan geometry: ceil(150000/512)
#define SRB     293

// ---------------- Phase A: partition edges into 512-row buckets --------------
// Proven parta core (LDS bucket count + rank scatter) + NEW: per-edge row-rank
// via RETURNING GLOBAL atomic on rowcnt[150K] (TCC pipe, overlaps the
// LDS-atomic-bound execution) stored as u8 in staging8. This removes BOTH of
// partb's per-edge LDS atomics (histogram + rank), ~90us of LDS-pipe serial
// time at the R4-measured ~3.4 cyc/lane-atomic throughput.
// Max row degree ~Poisson(26.7): P(deg>255) ~ 0 -> u8 rank safe.
__global__ __launch_bounds__(512) void k_parta(
        const int* __restrict__ row, const int* __restrict__ col,
        const float* __restrict__ vals, int* __restrict__ bcnt,
        unsigned int* __restrict__ rowcnt,
        unsigned long long* __restrict__ staging,
        unsigned char* __restrict__ staging8, int nnz) {
    __shared__ int cnt[512];
    __shared__ int base_s[512];
    int tid = threadIdx.x;
    cnt[tid] = 0;
    __syncthreads();
    int tile0 = blockIdx.x * 16384;
    for (int k = 0; k < 32; k++) {
        int e = tile0 + k * 512 + tid;
        if (e < nnz) atomicAdd(&cnt[row[e] >> 9], 1);
    }
    __syncthreads();
    int c_ = cnt[tid];
    base_s[tid] = c_ ? (tid * CAP + atomicAdd(&bcnt[tid], c_)) : 0;
    __syncthreads();
    cnt[tid] = 0;                                       // reuse as rank counter
    __syncthreads();
    for (int k = 0; k < 32; k++) {
        int e = tile0 + k * 512 + tid;
        if (e < nnz) {
            int r = row[e];
            int b = r >> 9;
            int rank = atomicAdd(&cnt[b], 1);
            int slot = base_s[b] + rank;
            unsigned int rkr = atomicAdd(&rowcnt[r], 1u);   // global, returning
            unsigned int key = ((unsigned int)(r & 511) << 18) | (unsigned int)col[e];
            unsigned long long rec = (unsigned long long)key
                                   | ((unsigned long long)__float_as_uint(vals[e]) << 32);
            staging[slot]  = rec;
            staging8[slot] = (unsigned char)rkr;
        }
    }
}

// ---------------- 3-kernel exclusive scan: rowcnt[150K] -> row_ptr -----------
__global__ __launch_bounds__(512) void k_rscanA(const unsigned int* __restrict__ rowcnt,
                                                int* __restrict__ bsum) {
    __shared__ int sh[512];
    int t = threadIdx.x;
    int i = blockIdx.x * 512 + t;
    sh[t] = (i < N_NODES) ? (int)rowcnt[i] : 0;
    __syncthreads();
    for (int off = 256; off > 0; off >>= 1) {
        if (t < off) sh[t] += sh[t + off];
        __syncthreads();
    }
    if (t == 0) bsum[blockIdx.x] = sh[0];
}
__global__ __launch_bounds__(512) void k_rscanB(int* __restrict__ bsum) {
    __shared__ int sh[512];
    int t = threadIdx.x;
    int v = (t < SRB) ? bsum[t] : 0;
    sh[t] = v;
    __syncthreads();
    for (int off = 1; off < 512; off <<= 1) {
        int u = (t >= off) ? sh[t - off] : 0;
        __syncthreads();
        sh[t] += u;
        __syncthreads();
    }
    if (t < SRB) bsum[t] = sh[t] - v;                   // exclusive block bases
}
__global__ __launch_bounds__(512) void k_rscanC(const unsigned int* __restrict__ rowcnt,
                                                const int* __restrict__ bsum,
                                                int* __restrict__ row_ptr) {
    __shared__ int sh[512];
    int t = threadIdx.x;
    int i = blockIdx.x * 512 + t;
    int v = (i < N_NODES) ? (int)rowcnt[i] : 0;
    sh[t] = v;
    __syncthreads();
    for (int off = 1; off < 512; off <<= 1) {
        int u = (t >= off) ? sh[t - off] : 0;
        __syncthreads();
        sh[t] += u;
        __syncthreads();
    }
    if (i < N_NODES) row_ptr[i] = bsum[blockIdx.x] + sh[t] - v;
    if (i == 0) row_ptr[N_NODES] = NNZV;
}

// ---------------- Phase B-lite: ZERO-ATOMIC scatter to CSR -------------------
// dst = row_ptr[row] + stored u8 row-rank. Pure streaming: 36 MB in, 32 MB
// out; writes land random-within-bucket (~109 KB CSR span) -> L2 write-merge
// profile identical to parta's staging writes (R11-proven OK).
__global__ __launch_bounds__(512) void k_partb_lite(
        const int* __restrict__ bcnt,
        const unsigned long long* __restrict__ staging,
        const unsigned char* __restrict__ staging8,
        const int* __restrict__ row_ptr,
        unsigned long long* __restrict__ edges) {
    int b = blockIdx.x;
    int n = bcnt[b];
    const unsigned long long* sb = staging  + (size_t)b * CAP;
    const unsigned char*      s8 = staging8 + (size_t)b * CAP;
    for (int i = threadIdx.x; i < n; i += 512) {
        unsigned long long rec = sb[i];
        unsigned int key = (unsigned int)rec;
        int r = (b << 9) + (int)(key >> 18);
        int dst = row_ptr[r] + (int)s8[i];
        edges[dst] = (rec & 0xFFFFFFFF00000000ull) | (key & 0x3FFFFu);
    }
}

// ---------------- single-row SpMM helper (R0-proven, used by batch kernel) ---
__device__ __forceinline__ float4 spmm_row(const int* row_ptr,
                                           const unsigned long long* edges,
                                           const float4* __restrict__ eu4,
                                           const float4* __restrict__ ei4s,
                                           int r, int lane) {
    int g = lane >> 4;
    int d = lane & 15;
    int start = row_ptr[r];
    int end   = row_ptr[r + 1];
    float4 acc = make_float4(0.f, 0.f, 0.f, 0.f);
    for (int e0 = start; e0 < end; e0 += 64) {
        int ei = e0 + lane;
        unsigned long long rec = 0ull;
        if (ei < end) rec = __builtin_nontemporal_load(edges + ei);
        int clo = (int)(rec & 0xffffffffull);
        int vhi = (int)(rec >> 32);
        int nleft = end - e0;
        int kmax = (nleft + 3) >> 2;          // uniform across the wave
        #pragma unroll 4
        for (int k = 0; k < kmax; k++) {
            int src = 4 * k + g;
            int cc = __shfl(clo, src);
            float vv = __int_as_float(__shfl(vhi, src));
            const float4* basep = (cc < N_USERS) ? eu4 : ei4s;
            float4 e = basep[cc * 16 + d];
            acc.x += vv * e.x;
            acc.y += vv * e.y;
            acc.z += vv * e.z;
            acc.w += vv * e.w;
        }
    }
    acc.x += __shfl_xor(acc.x, 16);
    acc.y += __shfl_xor(acc.y, 16);
    acc.z += __shfl_xor(acc.z, 16);
    acc.w += __shfl_xor(acc.w, 16);
    acc.x += __shfl_xor(acc.x, 32);
    acc.y += __shfl_xor(acc.y, 32);
    acc.z += __shfl_xor(acc.z, 32);
    acc.w += __shfl_xor(acc.w, 32);
    return acc;
}

// ---------------- 4-row-per-wave SpMM (layers 1 & 2, R6: 140us = wall) -------
// R6 A/B vs R0 proved this kernel sits at the ~3.67 TB/s L2-fill throughput
// wall for random gathers (4x ILP -> zero delta). Kept as-is.
__global__ void k_spmm4(const int* __restrict__ row_ptr,
                        const unsigned long long* __restrict__ edges,
                        const float4* __restrict__ eu4,
                        const float4* __restrict__ ei4s,
                        float4* __restrict__ Eout) {
    int lane = threadIdx.x & 63;
    int wv   = threadIdx.x >> 6;
    int rbase = (blockIdx.x * 4 + wv) * 4;       // 4 rows per wave
    if (rbase >= N_NODES) return;
    int g = lane >> 4;
    int d = lane & 15;
    int st[4], en[4], len[4];
    #pragma unroll
    for (int i = 0; i < 4; i++) {
        int r = rbase + i;
        if (r < N_NODES) { st[i] = row_ptr[r]; en[i] = row_ptr[r + 1]; }
        else             { st[i] = 0;          en[i] = 0; }
        len[i] = en[i] - st[i];
    }
    int maxlen = len[0];
    #pragma unroll
    for (int i = 1; i < 4; i++) maxlen = (len[i] > maxlen) ? len[i] : maxlen;

    float4 acc[4];
    #pragma unroll
    for (int i = 0; i < 4; i++) acc[i] = make_float4(0.f, 0.f, 0.f, 0.f);

    for (int off = 0; off < maxlen; off += 64) {
        int clo[4], vhi[4], kmax[4];
        #pragma unroll
        for (int i = 0; i < 4; i++) {
            int ei = st[i] + off + lane;
            unsigned long long rec = 0ull;
            if (ei < en[i]) rec = __builtin_nontemporal_load(edges + ei);
            clo[i] = (int)(rec & 0xffffffffull);
            vhi[i] = (int)(rec >> 32);
            int nleft = len[i] - off;
            if (nleft < 0) nleft = 0; else if (nleft > 64) nleft = 64;
            kmax[i] = (nleft + 3) >> 2;          // wave-uniform per row
        }
        int kmx = (maxlen - off + 3) >> 2; if (kmx > 16) kmx = 16;
        #pragma unroll 4
        for (int k = 0; k < kmx; k++) {
            int src = 4 * k + g;
            #pragma unroll
            for (int i = 0; i < 4; i++) {
                if (k < kmax[i]) {               // wave-uniform branch
                    int cc = __shfl(clo[i], src);
                    float vv = __int_as_float(__shfl(vhi[i], src));
                    const float4* bp = (cc < N_USERS) ? eu4 : ei4s;
                    float4 e = bp[cc * 16 + d];
                    acc[i].x += vv * e.x;
                    acc[i].y += vv * e.y;
                    acc[i].z += vv * e.z;
                    acc[i].w += vv * e.w;
                }
            }
        }
    }
    #pragma unroll
    for (int i = 0; i < 4; i++) {
        acc[i].x += __shfl_xor(acc[i].x, 16);
        acc[i].y += __shfl_xor(acc[i].y, 16);
        acc[i].z += __shfl_xor(acc[i].z, 16);
        acc[i].w += __shfl_xor(acc[i].w, 16);
        acc[i].x += __shfl_xor(acc[i].x, 32);
        acc[i].y += __shfl_xor(acc[i].y, 32);
        acc[i].z += __shfl_xor(acc[i].z, 32);
        acc[i].w += __shfl_xor(acc[i].w, 32);
    }
    if (lane < 16) {
        #pragma unroll
        for (int i = 0; i < 4; i++)
            if (rbase + i < N_NODES) Eout[(rbase + i) * 16 + lane] = acc[i];
    }
}

// --------- layer-3 SpMM restricted to batch rows, fused epilogue -------------
__global__ void k_spmm_batch(const int* __restrict__ row_ptr,
                             const unsigned long long* __restrict__ edges,
                             const float4* __restrict__ Ein,   // E2
                             const int* __restrict__ bu, const int* __restrict__ bp,
                             const int* __restrict__ bn,
                             float4* __restrict__ out) {
    int lane = threadIdx.x & 63;
    int j = blockIdx.x * 4 + (threadIdx.x >> 6);
    if (j >= 3 * BATCH) return;
    int r;
    if (j < BATCH)          r = bu[j];
    else if (j < 2 * BATCH) r = N_USERS + bp[j - BATCH];
    else                    r = N_USERS + bn[j - 2 * BATCH];
    float4 acc = spmm_row(row_ptr, edges, Ein, Ein, r, lane);
    if (lane < 16) {
        float4 e2 = Ein[r * 16 + lane];
        float4 o  = out[j * 16 + lane];
        o.x += 0.25f * (acc.x + e2.x);
        o.y += 0.25f * (acc.y + e2.y);
        o.z += 0.25f * (acc.z + e2.z);
        o.w += 0.25f * (acc.w + e2.w);
        out[j * 16 + lane] = o;
    }
}

// ---------------- init gather: out = 0.25 * E0[batch] (virtual concat) -------
__global__ void k_gather_init(const int* __restrict__ bu, const int* __restrict__ bp,
                              const int* __restrict__ bn,
                              const float4* __restrict__ eu4,
                              const float4* __restrict__ ei4s,
                              float4* __restrict__ out) {
    int idx = blockIdx.x * blockDim.x + threadIdx.x;
    if (idx >= 3 * BATCH * 16) return;
    int j = idx >> 4;
    int d = idx & 15;
    int node;
    if (j < BATCH)          node = bu[j];
    else if (j < 2 * BATCH) node = N_USERS + bp[j - BATCH];
    else                    node = N_USERS + bn[j - 2 * BATCH];
    const float4* basep = (node < N_USERS) ? eu4 : ei4s;
    float4 v = basep[node * 16 + d];
    v.x *= 0.25f; v.y *= 0.25f; v.z *= 0.25f; v.w *= 0.25f;
    out[idx] = v;
}

// ---------------- accumulate gather: out += 0.25 * E[batch] ------------------
__global__ void k_gather_acc(const int* __restrict__ bu, const int* __restrict__ bp,
                             const int* __restrict__ bn, const float4* __restrict__ E,
                             float4* __restrict__ out) {
    int idx = blockIdx.x * blockDim.x + threadIdx.x;
    if (idx >= 3 * BATCH * 16) return;
    int j = idx >> 4;
    int d = idx & 15;
    int node;
    if (j < BATCH)          node = bu[j];
    else if (j < 2 * BATCH) node = N_USERS + bp[j - BATCH];
    else                    node = N_USERS + bn[j - 2 * BATCH];
    float4 v = E[node * 16 + d];
    float4 o = out[idx];
    o.x += 0.25f * v.x; o.y += 0.25f * v.y; o.z += 0.25f * v.z; o.w += 0.25f * v.w;
    out[idx] = o;
}

extern "C" void kernel_launch(void* const* d_in, const int* in_sizes, int n_in,
                              void* d_out, int out_size, void* d_ws, size_t ws_size,
                              hipStream_t stream) {
    const int*   bu   = (const int*)d_in[0];
    const int*   bp   = (const int*)d_in[1];
    const int*   bn   = (const int*)d_in[2];
    const float* eu   = (const float*)d_in[3];
    const float* ei   = (const float*)d_in[4];
    const int*   row  = (const int*)d_in[5];
    const int*   col  = (const int*)d_in[6];
    const float* vals = (const float*)d_in[7];
    float* out = (float*)d_out;

    char* p = (char*)d_ws;
    auto alloc = [&](size_t nbytes) {
        void* r = (void*)p;
        p += (nbytes + 255) & ~(size_t)255;
        return r;
    };
    float*              E_a     = (float*)alloc((size_t)N_NODES * EMBED * 4);  // 38.4 MB
    float*              E_b     = (float*)alloc((size_t)N_NODES * EMBED * 4);  // 38.4 MB
    unsigned long long* edges   = (unsigned long long*)alloc((size_t)NNZV * 8);// 32.0 MB
    int*                row_ptr = (int*)alloc((N_NODES + 1) * 4);              // 0.6 MB
    unsigned int*       rowcnt  = (unsigned int*)alloc((size_t)N_NODES * 4);   // 0.6 MB
    int*                bcnt    = (int*)alloc(512 * 4);
    int*                bsum    = (int*)alloc((size_t)SRB * 4);
    (void)ws_size; (void)n_in; (void)in_sizes; (void)out_size;

    // Overlays (R2/R6-proven ~110 MB envelope):
    //  staging  (NBKT*CAP*8 = 37.8 MB) on E_b : dead after k_partb_lite,
    //           before layer-2 spmm writes E_b.
    //  staging8 (NBKT*CAP*1 =  4.7 MB) on E_a : dead after k_partb_lite,
    //           before layer-1 spmm writes E_a.
    unsigned long long* staging  = (unsigned long long*)E_b;
    unsigned char*      staging8 = (unsigned char*)E_a;

    const float4* eu4  = (const float4*)eu;
    const float4* ei4s = (const float4*)ei - (size_t)N_USERS * 16;  // pre-shifted

    const int nnz = NNZV;
    hipMemsetAsync(bcnt, 0, 512 * sizeof(int), stream);
    hipMemsetAsync(rowcnt, 0, (size_t)N_NODES * 4, stream);

    k_parta<<<(nnz + 16383) / 16384, 512, 0, stream>>>(
        row, col, vals, bcnt, rowcnt, staging, staging8, nnz);
    k_rscanA<<<SRB, 512, 0, stream>>>(rowcnt, bsum);
    k_rscanB<<<1, 512, 0, stream>>>(bsum);
    k_rscanC<<<SRB, 512, 0, stream>>>(rowcnt, bsum, row_ptr);
    k_partb_lite<<<NBKT, 512, 0, stream>>>(bcnt, staging, staging8, row_ptr, edges);

    // out = 0.25 * E0[batch]
    k_gather_init<<<(3 * BATCH * 16 + 255) / 256, 256, 0, stream>>>(
        bu, bp, bn, eu4, ei4s, (float4*)out);

    // layer 1: E1 = A * E0 (virtual concat input)
    k_spmm4<<<(N_NODES + 15) / 16, 256, 0, stream>>>(row_ptr, edges, eu4, ei4s,
                                                     (float4*)E_a);
    k_gather_acc<<<(3 * BATCH * 16 + 255) / 256, 256, 0, stream>>>(
        bu, bp, bn, (const float4*)E_a, (float4*)out);

    // layer 2: E2 = A * E1 (global node ids -> same base twice, no shift)
    k_spmm4<<<(N_NODES + 15) / 16, 256, 0, stream>>>(row_ptr, edges,
                                                     (const float4*)E_a,
                                                     (const float4*)E_a,
                                                     (float4*)E_b);

    // layer 3: only batch rows, fused  out += 0.25*E2[batch] + 0.25*E3[batch]
    k_spmm_batch<<<(3 * BATCH + 3) / 4, 256, 0, stream>>>(
        row_ptr, edges, (const float4*)E_b, bu, bp, bn, (float4*)out);
}

// Round 8
// 507.556 us; speedup vs baseline: 1.3410x; 1.3410x over previous
//
#include <hip/hip_runtime.h>

#define N_USERS 100000
#define N_ITEMS 50000
#define N_NODES 150000
#define EMBED   64
#define NNZV    4000000
#define BATCH   4096
// bucket = row / 586 : 586 rows per bucket, EXACTLY 256 buckets = 1 block/CU
// (R7 lesson: 293 buckets on 256 CUs quantized partb to 2x ideal duration).
#define BKW     586
#define NBKT    256
// staging capacity per bucket: mean 15625, sd ~125 -> +21 sigma, 64-aligned
#define CAP     18304

// ---------------- Phase A: partition edges into 586-row buckets --------------
// Proven R0/R6 mechanics (LDS bucket count + rank scatter), bucket width 586.
// NO returning global atomics (R7: +250MB fabric-write traffic, 3x slower).
// Plain (non-nt) staging stores: scattered 8B writes need L2 write-merge (R11).
// Record: low32 = rl<<18 | col (rl<586 -> 10 bits, col<150000 -> 18 bits),
// high32 = val bits.
__global__ __launch_bounds__(512) void k_parta(
        const int* __restrict__ row, const int* __restrict__ col,
        const float* __restrict__ vals, int* __restrict__ bcnt,
        unsigned long long* __restrict__ staging, int nnz) {
    __shared__ int cnt[NBKT];
    __shared__ int base_s[NBKT];
    int tid = threadIdx.x;
    if (tid < NBKT) cnt[tid] = 0;
    __syncthreads();
    int tile0 = blockIdx.x * 16384;
    for (int k = 0; k < 32; k++) {
        int e = tile0 + k * 512 + tid;
        if (e < nnz) atomicAdd(&cnt[row[e] / BKW], 1);
    }
    __syncthreads();
    if (tid < NBKT) {
        int c_ = cnt[tid];
        base_s[tid] = c_ ? (tid * CAP + atomicAdd(&bcnt[tid], c_)) : 0;
        cnt[tid] = 0;                                   // reuse as rank counter
    }
    __syncthreads();
    for (int k = 0; k < 32; k++) {
        int e = tile0 + k * 512 + tid;
        if (e < nnz) {
            int r = row[e];
            int b = r / BKW;
            int rank = atomicAdd(&cnt[b], 1);
            unsigned int key = ((unsigned int)(r - b * BKW) << 18) | (unsigned int)col[e];
            unsigned long long rec = (unsigned long long)key
                                   | ((unsigned long long)__float_as_uint(vals[e]) << 32);
            staging[base_s[b] + rank] = rec;
        }
    }
}

// ------- Phase B: bucket scan + per-bucket histogram/scan + local scatter ----
// One block per bucket, 256 blocks = 1/CU (no tail). 586 rows handled
// 2-rows-per-thread for the histogram/scan stages.
__global__ __launch_bounds__(512) void k_partb(
        const int* __restrict__ bcnt,
        const unsigned long long* __restrict__ staging,
        int* __restrict__ row_ptr,
        unsigned long long* __restrict__ edges) {
    __shared__ int s[512];
    __shared__ int cnt[BKW];
    __shared__ int cur[BKW];
    __shared__ int base_sh;
    int b = blockIdx.x;
    int t = threadIdx.x;

    // exclusive prefix of the 256 bucket counts at position b
    int v = (t < NBKT) ? bcnt[t] : 0;
    s[t] = v;
    __syncthreads();
    for (int off = 1; off < 512; off <<= 1) {
        int u = (t >= off) ? s[t - off] : 0;
        __syncthreads();
        s[t] += u;
        __syncthreads();
    }
    if (t == b) base_sh = s[t] - v;
    if (b == 0 && t == 0) row_ptr[N_NODES] = NNZV;
    __syncthreads();
    int base = base_sh;
    int n    = bcnt[b];
    const unsigned long long* sb = staging + (size_t)b * CAP;

    // per-bucket row histogram (586 rows, 2 per thread)
    int j0 = 2 * t, j1 = 2 * t + 1;
    if (j0 < BKW) cnt[j0] = 0;
    if (j1 < BKW) cnt[j1] = 0;
    __syncthreads();
    for (int i = t; i < n; i += 512)
        atomicAdd(&cnt[(unsigned int)sb[i] >> 18], 1);
    __syncthreads();
    // scan: each thread owns rows 2t, 2t+1
    int c0 = (j0 < BKW) ? cnt[j0] : 0;
    int c1 = (j1 < BKW) ? cnt[j1] : 0;
    int pair = c0 + c1;
    s[t] = pair;
    __syncthreads();
    for (int off = 1; off < 512; off <<= 1) {
        int u = (t >= off) ? s[t - off] : 0;
        __syncthreads();
        s[t] += u;
        __syncthreads();
    }
    int excl = s[t] - pair;
    if (j0 < BKW) cur[j0] = excl;
    if (j1 < BKW) cur[j1] = excl + c0;
    int r0 = b * BKW + j0;
    int r1 = b * BKW + j1;
    if (j0 < BKW && r0 < N_NODES) row_ptr[r0] = base + excl;
    if (j1 < BKW && r1 < N_NODES) row_ptr[r1] = base + excl + c0;
    __syncthreads();
    // rank scatter into dense CSR
    for (int i = t; i < n; i += 512) {
        unsigned long long rec = sb[i];
        unsigned int key = (unsigned int)rec;
        int rank = atomicAdd(&cur[key >> 18], 1);
        edges[base + rank] = (rec & 0xFFFFFFFF00000000ull) | (key & 0x3FFFFu);
    }
}

// ---------------- single-row SpMM helper (R0-proven, used by batch kernel) ---
__device__ __forceinline__ float4 spmm_row(const int* row_ptr,
                                           const unsigned long long* edges,
                                           const float4* __restrict__ eu4,
                                           const float4* __restrict__ ei4s,
                                           int r, int lane) {
    int g = lane >> 4;
    int d = lane & 15;
    int start = row_ptr[r];
    int end   = row_ptr[r + 1];
    float4 acc = make_float4(0.f, 0.f, 0.f, 0.f);
    for (int e0 = start; e0 < end; e0 += 64) {
        int ei = e0 + lane;
        unsigned long long rec = 0ull;
        if (ei < end) rec = __builtin_nontemporal_load(edges + ei);
        int clo = (int)(rec & 0xffffffffull);
        int vhi = (int)(rec >> 32);
        int nleft = end - e0;
        int kmax = (nleft + 3) >> 2;          // uniform across the wave
        #pragma unroll 4
        for (int k = 0; k < kmax; k++) {
            int src = 4 * k + g;
            int cc = __shfl(clo, src);
            float vv = __int_as_float(__shfl(vhi, src));
            const float4* basep = (cc < N_USERS) ? eu4 : ei4s;
            float4 e = basep[cc * 16 + d];
            acc.x += vv * e.x;
            acc.y += vv * e.y;
            acc.z += vv * e.z;
            acc.w += vv * e.w;
        }
    }
    acc.x += __shfl_xor(acc.x, 16);
    acc.y += __shfl_xor(acc.y, 16);
    acc.z += __shfl_xor(acc.z, 16);
    acc.w += __shfl_xor(acc.w, 16);
    acc.x += __shfl_xor(acc.x, 32);
    acc.y += __shfl_xor(acc.y, 32);
    acc.z += __shfl_xor(acc.z, 32);
    acc.w += __shfl_xor(acc.w, 32);
    return acc;
}

// ---------------- 4-row-per-wave SpMM (layers 1 & 2) -------------------------
// R0 vs R6 A/B: this kernel sits at the ~3.67 TB/s L2-fill throughput wall
// for random gathers (4x ILP -> zero delta). Kept as-is.
__global__ void k_spmm4(const int* __restrict__ row_ptr,
                        const unsigned long long* __restrict__ edges,
                        const float4* __restrict__ eu4,
                        const float4* __restrict__ ei4s,
                        float4* __restrict__ Eout) {
    int lane = threadIdx.x & 63;
    int wv   = threadIdx.x >> 6;
    int rbase = (blockIdx.x * 4 + wv) * 4;       // 4 rows per wave
    if (rbase >= N_NODES) return;
    int g = lane >> 4;
    int d = lane & 15;
    int st[4], en[4], len[4];
    #pragma unroll
    for (int i = 0; i < 4; i++) {
        int r = rbase + i;
        if (r < N_NODES) { st[i] = row_ptr[r]; en[i] = row_ptr[r + 1]; }
        else             { st[i] = 0;          en[i] = 0; }
        len[i] = en[i] - st[i];
    }
    int maxlen = len[0];
    #pragma unroll
    for (int i = 1; i < 4; i++) maxlen = (len[i] > maxlen) ? len[i] : maxlen;

    float4 acc[4];
    #pragma unroll
    for (int i = 0; i < 4; i++) acc[i] = make_float4(0.f, 0.f, 0.f, 0.f);

    for (int off = 0; off < maxlen; off += 64) {
        int clo[4], vhi[4], kmax[4];
        #pragma unroll
        for (int i = 0; i < 4; i++) {
            int ei = st[i] + off + lane;
            unsigned long long rec = 0ull;
            if (ei < en[i]) rec = __builtin_nontemporal_load(edges + ei);
            clo[i] = (int)(rec & 0xffffffffull);
            vhi[i] = (int)(rec >> 32);
            int nleft = len[i] - off;
            if (nleft < 0) nleft = 0; else if (nleft > 64) nleft = 64;
            kmax[i] = (nleft + 3) >> 2;          // wave-uniform per row
        }
        int kmx = (maxlen - off + 3) >> 2; if (kmx > 16) kmx = 16;
        #pragma unroll 4
        for (int k = 0; k < kmx; k++) {
            int src = 4 * k + g;
            #pragma unroll
            for (int i = 0; i < 4; i++) {
                if (k < kmax[i]) {               // wave-uniform branch
                    int cc = __shfl(clo[i], src);
                    float vv = __int_as_float(__shfl(vhi[i], src));
                    const float4* bp = (cc < N_USERS) ? eu4 : ei4s;
                    float4 e = bp[cc * 16 + d];
                    acc[i].x += vv * e.x;
                    acc[i].y += vv * e.y;
                    acc[i].z += vv * e.z;
                    acc[i].w += vv * e.w;
                }
            }
        }
    }
    #pragma unroll
    for (int i = 0; i < 4; i++) {
        acc[i].x += __shfl_xor(acc[i].x, 16);
        acc[i].y += __shfl_xor(acc[i].y, 16);
        acc[i].z += __shfl_xor(acc[i].z, 16);
        acc[i].w += __shfl_xor(acc[i].w, 16);
        acc[i].x += __shfl_xor(acc[i].x, 32);
        acc[i].y += __shfl_xor(acc[i].y, 32);
        acc[i].z += __shfl_xor(acc[i].z, 32);
        acc[i].w += __shfl_xor(acc[i].w, 32);
    }
    if (lane < 16) {
        #pragma unroll
        for (int i = 0; i < 4; i++)
            if (rbase + i < N_NODES) Eout[(rbase + i) * 16 + lane] = acc[i];
    }
}

// --------- layer-3 SpMM restricted to batch rows, fused epilogue -------------
__global__ void k_spmm_batch(const int* __restrict__ row_ptr,
                             const unsigned long long* __restrict__ edges,
                             const float4* __restrict__ Ein,   // E2
                             const int* __restrict__ bu, const int* __restrict__ bp,
                             const int* __restrict__ bn,
                             float4* __restrict__ out) {
    int lane = threadIdx.x & 63;
    int j = blockIdx.x * 4 + (threadIdx.x >> 6);
    if (j >= 3 * BATCH) return;
    int r;
    if (j < BATCH)          r = bu[j];
    else if (j < 2 * BATCH) r = N_USERS + bp[j - BATCH];
    else                    r = N_USERS + bn[j - 2 * BATCH];
    float4 acc = spmm_row(row_ptr, edges, Ein, Ein, r, lane);
    if (lane < 16) {
        float4 e2 = Ein[r * 16 + lane];
        float4 o  = out[j * 16 + lane];
        o.x += 0.25f * (acc.x + e2.x);
        o.y += 0.25f * (acc.y + e2.y);
        o.z += 0.25f * (acc.z + e2.z);
        o.w += 0.25f * (acc.w + e2.w);
        out[j * 16 + lane] = o;
    }
}

// ---------------- init gather: out = 0.25 * E0[batch] (virtual concat) -------
__global__ void k_gather_init(const int* __restrict__ bu, const int* __restrict__ bp,
                              const int* __restrict__ bn,
                              const float4* __restrict__ eu4,
                              const float4* __restrict__ ei4s,
                              float4* __restrict__ out) {
    int idx = blockIdx.x * blockDim.x + threadIdx.x;
    if (idx >= 3 * BATCH * 16) return;
    int j = idx >> 4;
    int d = idx & 15;
    int node;
    if (j < BATCH)          node = bu[j];
    else if (j < 2 * BATCH) node = N_USERS + bp[j - BATCH];
    else                    node = N_USERS + bn[j - 2 * BATCH];
    const float4* basep = (node < N_USERS) ? eu4 : ei4s;
    float4 v = basep[node * 16 + d];
    v.x *= 0.25f; v.y *= 0.25f; v.z *= 0.25f; v.w *= 0.25f;
    out[idx] = v;
}

// ---------------- accumulate gather: out += 0.25 * E[batch] ------------------
__global__ void k_gather_acc(const int* __restrict__ bu, const int* __restrict__ bp,
                             const int* __restrict__ bn, const float4* __restrict__ E,
                             float4* __restrict__ out) {
    int idx = blockIdx.x * blockDim.x + threadIdx.x;
    if (idx >= 3 * BATCH * 16) return;
    int j = idx >> 4;
    int d = idx & 15;
    int node;
    if (j < BATCH)          node = bu[j];
    else if (j < 2 * BATCH) node = N_USERS + bp[j - BATCH];
    else                    node = N_USERS + bn[j - 2 * BATCH];
    float4 v = E[node * 16 + d];
    float4 o = out[idx];
    o.x += 0.25f * v.x; o.y += 0.25f * v.y; o.z += 0.25f * v.z; o.w += 0.25f * v.w;
    out[idx] = o;
}

extern "C" void kernel_launch(void* const* d_in, const int* in_sizes, int n_in,
                              void* d_out, int out_size, void* d_ws, size_t ws_size,
                              hipStream_t stream) {
    const int*   bu   = (const int*)d_in[0];
    const int*   bp   = (const int*)d_in[1];
    const int*   bn   = (const int*)d_in[2];
    const float* eu   = (const float*)d_in[3];
    const float* ei   = (const float*)d_in[4];
    const int*   row  = (const int*)d_in[5];
    const int*   col  = (const int*)d_in[6];
    const float* vals = (const float*)d_in[7];
    float* out = (float*)d_out;

    char* p = (char*)d_ws;
    auto alloc = [&](size_t nbytes) {
        void* r = (void*)p;
        p += (nbytes + 255) & ~(size_t)255;
        return r;
    };
    float*              E_a     = (float*)alloc((size_t)N_NODES * EMBED * 4);  // 38.4 MB
    float*              E_b     = (float*)alloc((size_t)N_NODES * EMBED * 4);  // 38.4 MB
    unsigned long long* edges   = (unsigned long long*)alloc((size_t)NNZV * 8);// 32.0 MB
    int*                row_ptr = (int*)alloc((N_NODES + 1) * 4);
    int*                bcnt    = (int*)alloc(NBKT * 4);
    (void)ws_size; (void)n_in; (void)in_sizes; (void)out_size;

    // staging (NBKT*CAP*8 = 37.5 MB) overlays E_b (38.4 MB): staging is dead
    // after k_partb, before layer-2 spmm writes E_b (same stream => ordered).
    // Footprint = the R0/R6-proven ~109 MB envelope.
    unsigned long long* staging = (unsigned long long*)E_b;

    const float4* eu4  = (const float4*)eu;
    const float4* ei4s = (const float4*)ei - (size_t)N_USERS * 16;  // pre-shifted

    const int nnz = NNZV;
    hipMemsetAsync(bcnt, 0, NBKT * sizeof(int), stream);

    k_parta<<<(nnz + 16383) / 16384, 512, 0, stream>>>(row, col, vals, bcnt, staging, nnz);
    k_partb<<<NBKT, 512, 0, stream>>>(bcnt, staging, row_ptr, edges);

    // out = 0.25 * E0[batch]
    k_gather_init<<<(3 * BATCH * 16 + 255) / 256, 256, 0, stream>>>(
        bu, bp, bn, eu4, ei4s, (float4*)out);

    // layer 1: E1 = A * E0 (virtual concat input)
    k_spmm4<<<(N_NODES + 15) / 16, 256, 0, stream>>>(row_ptr, edges, eu4, ei4s,
                                                     (float4*)E_a);
    k_gather_acc<<<(3 * BATCH * 16 + 255) / 256, 256, 0, stream>>>(
        bu, bp, bn, (const float4*)E_a, (float4*)out);

    // layer 2: E2 = A * E1 (global node ids -> same base twice, no shift)
    k_spmm4<<<(N_NODES + 15) / 16, 256, 0, stream>>>(row_ptr, edges,
                                                     (const float4*)E_a,
                                                     (const float4*)E_a,
                                                     (float4*)E_b);

    // layer 3: only batch rows, fused  out += 0.25*E2[batch] + 0.25*E3[batch]
    k_spmm_batch<<<(3 * BATCH + 3) / 4, 256, 0, stream>>>(
        row_ptr, edges, (const float4*)E_b, bu, bp, bn, (float4*)out);
}